// Round 4
// baseline (551.135 us; speedup 1.0000x reference)
//
#include <hip/hip_runtime.h>
#include <math.h>

#define N_NODES 50000
#define N_EDGES 800000
#define IN_F 768
#define HID 128
#define CLS 40
#define CLSP 48
#define EPS 1e-5f
#define LNS 133  // padded LDS stride for gemm2ln tile

typedef __attribute__((ext_vector_type(8))) short short8;
typedef __attribute__((ext_vector_type(4))) float f32x4;

__device__ inline unsigned short f2bf(float f) {
    union { float f; unsigned u; } x;
    x.f = f;
    unsigned u = x.u;
    return (unsigned short)((u + 0x7FFF + ((u >> 16) & 1)) >> 16);
}

__device__ inline float bf2f(unsigned short u) {
    union { unsigned u; float f; } x;
    x.u = ((unsigned)u) << 16;
    return x.f;
}

__device__ inline unsigned pack2bf(float a, float b) {
    return (unsigned)f2bf(a) | ((unsigned)f2bf(b) << 16);
}

// ---------------- degree ----------------

__global__ void k_deg(const int* __restrict__ src, const int* __restrict__ dst,
                      int* __restrict__ deg_out, int* __restrict__ deg_in) {
    int e = blockIdx.x * 256 + threadIdx.x;
    if (e < N_EDGES) {
        atomicAdd(&deg_out[src[e]], 1);
        atomicAdd(&deg_in[dst[e]], 1);
    }
}

// ---------------- fused scan + rsqrt (single block, 1024 threads) ----------------
// row_ptr = exclusive prefix of deg_in; do_is/di_is = rsqrt(max(deg,1))

__global__ __launch_bounds__(1024) void k_scan(const int* __restrict__ deg_in,
                                               const int* __restrict__ deg_out,
                                               int* __restrict__ row_ptr,
                                               float* __restrict__ do_is,
                                               float* __restrict__ di_is) {
    __shared__ int ps[1024];
    int t = threadIdx.x;
    const int CH = (N_NODES + 1023) / 1024;  // 49
    int b0 = t * CH;
    int s = 0;
    for (int i = 0; i < CH; i++) {
        int idx = b0 + i;
        if (idx < N_NODES) s += deg_in[idx];
    }
    ps[t] = s;
    __syncthreads();
    for (int off = 1; off < 1024; off <<= 1) {
        int v = 0;
        if (t >= off) v = ps[t - off];
        __syncthreads();
        if (t >= off) ps[t] += v;
        __syncthreads();
    }
    int run = (t == 0) ? 0 : ps[t - 1];
    for (int i = 0; i < CH; i++) {
        int idx = b0 + i;
        if (idx < N_NODES) {
            int d = deg_in[idx];
            row_ptr[idx] = run;
            run += d;
            di_is[idx] = rsqrtf((float)max(d, 1));
            do_is[idx] = rsqrtf((float)max(deg_out[idx], 1));
        }
    }
    if (t == 0) row_ptr[N_NODES] = N_EDGES;
}

__global__ void k_fill(const int* __restrict__ src, const int* __restrict__ dst,
                       const int* __restrict__ row_ptr, int* __restrict__ cnt,
                       int* __restrict__ col) {
    int e = blockIdx.x * 256 + threadIdx.x;
    if (e < N_EDGES) {
        int d = dst[e];
        int pos = row_ptr[d] + atomicAdd(&cnt[d], 1);
        col[pos] = src[e];
    }
}

// ---------------- fused LN(768) + bf16 convert (wave per row) ----------------

__global__ void k_lncvt(const float* __restrict__ feat, const float* __restrict__ g,
                        const float* __restrict__ b, unsigned short* __restrict__ Abf) {
    int wid = (blockIdx.x * 256 + threadIdx.x) >> 6;
    int lane = threadIdx.x & 63;
    if (wid >= N_NODES) return;
    const float4* x4 = (const float4*)(feat + (size_t)wid * IN_F);
    float4 v[3];
    float s = 0.f, q = 0.f;
#pragma unroll
    for (int i = 0; i < 3; i++) {
        float4 t = x4[lane + 64 * i];
        v[i] = t;
        s += t.x + t.y + t.z + t.w;
        q += t.x * t.x + t.y * t.y + t.z * t.z + t.w * t.w;
    }
#pragma unroll
    for (int m = 1; m < 64; m <<= 1) {
        s += __shfl_xor(s, m);
        q += __shfl_xor(q, m);
    }
    float mu = s * (1.f / (float)IN_F);
    float var = q * (1.f / (float)IN_F) - mu * mu;
    float rstd = rsqrtf(var + EPS);
    ushort4* orow = (ushort4*)(Abf + (size_t)wid * IN_F);
    const float4* g4 = (const float4*)g;
    const float4* b4 = (const float4*)b;
#pragma unroll
    for (int i = 0; i < 3; i++) {
        int f = lane + 64 * i;
        float4 gg = g4[f];
        float4 bb = b4[f];
        ushort4 o;
        o.x = f2bf((v[i].x - mu) * rstd * gg.x + bb.x);
        o.y = f2bf((v[i].y - mu) * rstd * gg.y + bb.y);
        o.z = f2bf((v[i].z - mu) * rstd * gg.z + bb.z);
        o.w = f2bf((v[i].w - mu) * rstd * gg.w + bb.w);
        orow[f] = o;
    }
}

// ---------------- all weight transposes+converts in one kernel ----------------
// Wt layout [Cp][K] bf16 from W [K][C] f32

__global__ void k_cvtW_all(const float* __restrict__ W0, const float* __restrict__ W1,
                           const float* __restrict__ W2, unsigned short* __restrict__ Wt0,
                           unsigned short* __restrict__ Wt1, unsigned short* __restrict__ Wt2) {
    int idx = blockIdx.x * 256 + threadIdx.x;
    const int S0 = IN_F * HID;          // 98304
    const int S1 = S0 + HID * HID;      // +16384
    const int S2 = S1 + HID * CLSP;     // +6144
    if (idx < S0) {
        int c = idx / IN_F, k = idx % IN_F;
        Wt0[idx] = f2bf(W0[(size_t)k * HID + c]);
    } else if (idx < S1) {
        int j = idx - S0;
        int c = j / HID, k = j % HID;
        Wt1[j] = f2bf(W1[(size_t)k * HID + c]);
    } else if (idx < S2) {
        int j = idx - S1;
        int c = j / HID, k = j % HID;
        Wt2[j] = (c < CLS) ? f2bf(W2[(size_t)k * CLS + c]) : (unsigned short)0;
    }
}

// ---------------- GEMM1 (MFMA): h0 = bf16( (Abf @ Wt0^T) * do_is[row] ) ----------------

__global__ void k_gemm1_mfma(const unsigned short* __restrict__ Abf,
                             const unsigned short* __restrict__ Wt,
                             const float* __restrict__ do_is,
                             unsigned short* __restrict__ out) {
    int t = threadIdx.x;
    int w = t >> 6, l = t & 63;
    int r0 = blockIdx.x * 64;
    int c0 = w * 32;
    int lrow = l & 15;
    int lk8 = (l >> 4);

    const short8* ap[4];
#pragma unroll
    for (int m = 0; m < 4; m++) {
        int row = r0 + m * 16 + lrow;
        if (row > N_NODES - 1) row = N_NODES - 1;
        ap[m] = (const short8*)(Abf + (size_t)row * IN_F) + lk8;
    }
    const short8* bp[2];
#pragma unroll
    for (int n = 0; n < 2; n++) {
        int colr = c0 + n * 16 + lrow;
        bp[n] = (const short8*)(Wt + (size_t)colr * IN_F) + lk8;
    }

    f32x4 acc[4][2] = {};
#pragma unroll
    for (int k0 = 0; k0 < IN_F / 8; k0 += 4) {
        short8 bv[2];
        bv[0] = bp[0][k0];
        bv[1] = bp[1][k0];
#pragma unroll
        for (int m = 0; m < 4; m++) {
            short8 av = ap[m][k0];
            acc[m][0] = __builtin_amdgcn_mfma_f32_16x16x32_bf16(av, bv[0], acc[m][0], 0, 0, 0);
            acc[m][1] = __builtin_amdgcn_mfma_f32_16x16x32_bf16(av, bv[1], acc[m][1], 0, 0, 0);
        }
    }

#pragma unroll
    for (int m = 0; m < 4; m++) {
#pragma unroll
        for (int j = 0; j < 4; j++) {
            int row = r0 + m * 16 + (l >> 4) * 4 + j;
            if (row < N_NODES) {
                float s = do_is[row];
                out[(size_t)row * HID + c0 + (l & 15)] = f2bf(acc[m][0][j] * s);
                out[(size_t)row * HID + c0 + 16 + (l & 15)] = f2bf(acc[m][1][j] * s);
            }
        }
    }
}

// ---------------- GEMM2 + LN + ReLU fused ----------------
// h1 = bf16( relu( LN( (hb@Wt1^T) * di_is[row] ) ) * do_is[row] )

__global__ void k_gemm2ln(const unsigned short* __restrict__ A,
                          const unsigned short* __restrict__ Wt,
                          const float* __restrict__ di_is, const float* __restrict__ do_is,
                          const float* __restrict__ g, const float* __restrict__ b,
                          unsigned* __restrict__ out) {
    __shared__ float tile[64 * LNS];
    int t = threadIdx.x;
    int w = t >> 6, l = t & 63;
    int r0 = blockIdx.x * 64;
    int c0 = w * 32;
    int lrow = l & 15;
    int lk8 = (l >> 4);

    const short8* ap[4];
#pragma unroll
    for (int m = 0; m < 4; m++) {
        int row = r0 + m * 16 + lrow;
        if (row > N_NODES - 1) row = N_NODES - 1;
        ap[m] = (const short8*)(A + (size_t)row * HID) + lk8;
    }
    const short8* bp[2];
#pragma unroll
    for (int n = 0; n < 2; n++) {
        int colr = c0 + n * 16 + lrow;
        bp[n] = (const short8*)(Wt + (size_t)colr * HID) + lk8;
    }

    f32x4 acc[4][2] = {};
#pragma unroll
    for (int k0 = 0; k0 < HID / 8; k0 += 4) {
        short8 bv[2];
        bv[0] = bp[0][k0];
        bv[1] = bp[1][k0];
#pragma unroll
        for (int m = 0; m < 4; m++) {
            short8 av = ap[m][k0];
            acc[m][0] = __builtin_amdgcn_mfma_f32_16x16x32_bf16(av, bv[0], acc[m][0], 0, 0, 0);
            acc[m][1] = __builtin_amdgcn_mfma_f32_16x16x32_bf16(av, bv[1], acc[m][1], 0, 0, 0);
        }
    }

    // scaled values -> LDS tile
#pragma unroll
    for (int m = 0; m < 4; m++) {
#pragma unroll
        for (int j = 0; j < 4; j++) {
            int rl = m * 16 + (l >> 4) * 4 + j;
            int grow = r0 + rl;
            float s = di_is[(grow < N_NODES) ? grow : (N_NODES - 1)];
            tile[rl * LNS + c0 + (l & 15)] = acc[m][0][j] * s;
            tile[rl * LNS + c0 + 16 + (l & 15)] = acc[m][1][j] * s;
        }
    }
    __syncthreads();

    // LN: wave w owns rows w*16..w*16+15; lanes {r, r+16, r+32, r+48} cover cols q*32..+31
    int r = w * 16 + (l & 15);
    int q = l >> 4;
    float s1 = 0.f, s2 = 0.f;
#pragma unroll
    for (int c = 0; c < 32; c++) {
        float v = tile[r * LNS + q * 32 + c];
        s1 += v;
        s2 += v * v;
    }
    s1 += __shfl_xor(s1, 16); s2 += __shfl_xor(s2, 16);
    s1 += __shfl_xor(s1, 32); s2 += __shfl_xor(s2, 32);
    float mu = s1 * (1.f / 128.f);
    float var = s2 * (1.f / 128.f) - mu * mu;
    float rstd = rsqrtf(var + EPS);
    int grow = r0 + r;
    if (grow < N_NODES) {
        float sc = do_is[grow];
        unsigned* orow = out + (size_t)grow * 64 + q * 16;
        const float2* g2 = (const float2*)(g + q * 32);
        const float2* b2v = (const float2*)(b + q * 32);
#pragma unroll
        for (int cc = 0; cc < 16; cc++) {
            float v0 = tile[r * LNS + q * 32 + 2 * cc];
            float v1 = tile[r * LNS + q * 32 + 2 * cc + 1];
            float2 gg = g2[cc];
            float2 bb = b2v[cc];
            float y0 = fmaxf((v0 - mu) * rstd * gg.x + bb.x, 0.f) * sc;
            float y1 = fmaxf((v1 - mu) * rstd * gg.y + bb.y, 0.f) * sc;
            orow[cc] = pack2bf(y0, y1);
        }
    }
}

// ---------------- GEMM3 (MFMA): hc = bf16(h1 @ Wt2^T)  [M,128]x[128,40->48] ----------------

__global__ void k_gemm3_mfma(const unsigned short* __restrict__ A,
                             const unsigned short* __restrict__ Wt,
                             unsigned short* __restrict__ out) {
    int t = threadIdx.x;
    int w = t >> 6, l = t & 63;
    int r0 = blockIdx.x * 64 + w * 16;
    int lrow = l & 15;
    int lk8 = (l >> 4);

    int arow = r0 + lrow;
    if (arow > N_NODES - 1) arow = N_NODES - 1;
    const short8* ap = (const short8*)(A + (size_t)arow * HID) + lk8;
    const short8* bp[3];
#pragma unroll
    for (int n = 0; n < 3; n++) {
        int colr = n * 16 + lrow;
        bp[n] = (const short8*)(Wt + (size_t)colr * HID) + lk8;
    }

    f32x4 acc[3] = {};
#pragma unroll
    for (int k0 = 0; k0 < HID / 8; k0 += 4) {
        short8 av = ap[k0];
#pragma unroll
        for (int n = 0; n < 3; n++) {
            acc[n] = __builtin_amdgcn_mfma_f32_16x16x32_bf16(av, bp[n][k0], acc[n], 0, 0, 0);
        }
    }

#pragma unroll
    for (int n = 0; n < 3; n++) {
        int col = n * 16 + (l & 15);
        if (col < CLS) {
#pragma unroll
            for (int j = 0; j < 4; j++) {
                int row = r0 + (l >> 4) * 4 + j;
                if (row < N_NODES) out[(size_t)row * CLS + col] = f2bf(acc[n][j]);
            }
        }
    }
}

// ---------------- fused agg + LN + ReLU (layer 0), wave per node, 4x unrolled ----------------

__global__ void k_aggln(const unsigned short* __restrict__ h, const int* __restrict__ row_ptr,
                        const int* __restrict__ col, const float* __restrict__ di_is,
                        const float* __restrict__ do_is, const float* __restrict__ g,
                        const float* __restrict__ b, unsigned* __restrict__ out) {
    int wid = (blockIdx.x * blockDim.x + threadIdx.x) >> 6;
    int lane = threadIdx.x & 63;
    if (wid >= N_NODES) return;
    int s0 = row_ptr[wid], e0 = row_ptr[wid + 1];
    const unsigned* h2 = (const unsigned*)h;
    float ax = 0.f, ay = 0.f;
    int i = s0;
    for (; i + 3 < e0; i += 4) {
        int c0_ = col[i], c1_ = col[i + 1], c2_ = col[i + 2], c3_ = col[i + 3];
        unsigned u0 = h2[(size_t)c0_ * 64 + lane];
        unsigned u1 = h2[(size_t)c1_ * 64 + lane];
        unsigned u2 = h2[(size_t)c2_ * 64 + lane];
        unsigned u3 = h2[(size_t)c3_ * 64 + lane];
        ax += bf2f((unsigned short)(u0 & 0xFFFF)) + bf2f((unsigned short)(u1 & 0xFFFF)) +
              bf2f((unsigned short)(u2 & 0xFFFF)) + bf2f((unsigned short)(u3 & 0xFFFF));
        ay += bf2f((unsigned short)(u0 >> 16)) + bf2f((unsigned short)(u1 >> 16)) +
              bf2f((unsigned short)(u2 >> 16)) + bf2f((unsigned short)(u3 >> 16));
    }
    for (; i < e0; i++) {
        unsigned u = h2[(size_t)col[i] * 64 + lane];
        ax += bf2f((unsigned short)(u & 0xFFFF));
        ay += bf2f((unsigned short)(u >> 16));
    }
    float di = di_is[wid];
    ax *= di; ay *= di;
    float s = ax + ay;
    float q = ax * ax + ay * ay;
#pragma unroll
    for (int m = 1; m < 64; m <<= 1) {
        s += __shfl_xor(s, m);
        q += __shfl_xor(q, m);
    }
    float mu = s * (1.f / 128.f);
    float var = q * (1.f / 128.f) - mu * mu;
    float rstd = rsqrtf(var + EPS);
    float2 gg = ((const float2*)g)[lane];
    float2 bb = ((const float2*)b)[lane];
    float sc = do_is[wid];
    float y0 = fmaxf((ax - mu) * rstd * gg.x + bb.x, 0.f) * sc;
    float y1 = fmaxf((ay - mu) * rstd * gg.y + bb.y, 0.f) * sc;
    out[(size_t)wid * 64 + lane] = pack2bf(y0, y1);
}

// ---------------- agg (layer 1), bf16 raw-sum out, wave per node, 4x unrolled ----------------

__global__ void k_agg128b(const unsigned short* __restrict__ h, const int* __restrict__ row_ptr,
                          const int* __restrict__ col, unsigned* __restrict__ out) {
    int wid = (blockIdx.x * blockDim.x + threadIdx.x) >> 6;
    int lane = threadIdx.x & 63;
    if (wid >= N_NODES) return;
    int s0 = row_ptr[wid], e0 = row_ptr[wid + 1];
    const unsigned* h2 = (const unsigned*)h;
    float ax = 0.f, ay = 0.f;
    int i = s0;
    for (; i + 3 < e0; i += 4) {
        int c0_ = col[i], c1_ = col[i + 1], c2_ = col[i + 2], c3_ = col[i + 3];
        unsigned u0 = h2[(size_t)c0_ * 64 + lane];
        unsigned u1 = h2[(size_t)c1_ * 64 + lane];
        unsigned u2 = h2[(size_t)c2_ * 64 + lane];
        unsigned u3 = h2[(size_t)c3_ * 64 + lane];
        ax += bf2f((unsigned short)(u0 & 0xFFFF)) + bf2f((unsigned short)(u1 & 0xFFFF)) +
              bf2f((unsigned short)(u2 & 0xFFFF)) + bf2f((unsigned short)(u3 & 0xFFFF));
        ay += bf2f((unsigned short)(u0 >> 16)) + bf2f((unsigned short)(u1 >> 16)) +
              bf2f((unsigned short)(u2 >> 16)) + bf2f((unsigned short)(u3 >> 16));
    }
    for (; i < e0; i++) {
        unsigned u = h2[(size_t)col[i] * 64 + lane];
        ax += bf2f((unsigned short)(u & 0xFFFF));
        ay += bf2f((unsigned short)(u >> 16));
    }
    out[(size_t)wid * 64 + lane] = pack2bf(ax, ay);
}

// ---------------- agg (layer 2), 40 feats + bias, f32 out, wave per node, 4x unrolled ----------------

__global__ void k_agg40b(const unsigned short* __restrict__ h, const int* __restrict__ row_ptr,
                         const int* __restrict__ col, const float* __restrict__ di_is,
                         const float* __restrict__ b2, float* __restrict__ out) {
    int wid = (blockIdx.x * blockDim.x + threadIdx.x) >> 6;
    int lane = threadIdx.x & 63;
    if (wid >= N_NODES) return;
    if (lane < CLS) {
        int s0 = row_ptr[wid], e0 = row_ptr[wid + 1];
        float acc = 0.f;
        int i = s0;
        for (; i + 3 < e0; i += 4) {
            int c0_ = col[i], c1_ = col[i + 1], c2_ = col[i + 2], c3_ = col[i + 3];
            float v0 = bf2f(h[(size_t)c0_ * CLS + lane]);
            float v1 = bf2f(h[(size_t)c1_ * CLS + lane]);
            float v2 = bf2f(h[(size_t)c2_ * CLS + lane]);
            float v3 = bf2f(h[(size_t)c3_ * CLS + lane]);
            acc += v0 + v1 + v2 + v3;
        }
        for (; i < e0; i++) acc += bf2f(h[(size_t)col[i] * CLS + lane]);
        out[(size_t)wid * CLS + lane] = acc * di_is[wid] + b2[lane];
    }
}

// ---------------- launch ----------------

extern "C" void kernel_launch(void* const* d_in, const int* in_sizes, int n_in,
                              void* d_out, int out_size, void* d_ws, size_t ws_size,
                              hipStream_t stream) {
    (void)in_sizes; (void)n_in; (void)out_size; (void)ws_size;
    const float* feat = (const float*)d_in[0];
    const int*   src  = (const int*)d_in[1];
    const int*   dst  = (const int*)d_in[2];
    const float* W0   = (const float*)d_in[3];
    const float* W1   = (const float*)d_in[4];
    const float* W2   = (const float*)d_in[5];
    const float* b2   = (const float*)d_in[6];
    const float* g_in = (const float*)d_in[7];
    const float* b_in = (const float*)d_in[8];
    const float* g0   = (const float*)d_in[9];
    const float* b0   = (const float*)d_in[10];
    const float* g1   = (const float*)d_in[11];
    const float* b1   = (const float*)d_in[12];
    float* out = (float*)d_out;

    char* w = (char*)d_ws;
    size_t off = 0;
    auto take = [&](size_t bytes) -> void* {
        void* p = w + off;
        off += (bytes + 255) & ~(size_t)255;
        return p;
    };
    // contiguous int region for one memset: deg_out, deg_in, cnt
    const size_t SZN = ((size_t)N_NODES * 4 + 255) & ~(size_t)255;
    char* zblk      = (char*)take(3 * SZN);
    int*  deg_out_i = (int*)zblk;
    int*  deg_in_i  = (int*)(zblk + SZN);
    int*  cnt       = (int*)(zblk + 2 * SZN);

    float* do_is     = (float*)take((size_t)N_NODES * 4);
    float* di_is     = (float*)take((size_t)N_NODES * 4);
    int*   row_ptr   = (int*)take((size_t)(N_NODES + 1) * 4);
    int*   col       = (int*)take((size_t)N_EDGES * 4);
    unsigned short* Abf = (unsigned short*)take((size_t)N_NODES * IN_F * 2);
    unsigned short* Wt0 = (unsigned short*)take((size_t)IN_F * HID * 2);
    unsigned short* Wt1 = (unsigned short*)take((size_t)HID * HID * 2);
    unsigned short* Wt2 = (unsigned short*)take((size_t)HID * CLSP * 2);
    unsigned short* h0  = (unsigned short*)take((size_t)N_NODES * HID * 2);
    unsigned short* h1  = (unsigned short*)take((size_t)N_NODES * HID * 2);
    unsigned short* hb  = (unsigned short*)take((size_t)N_NODES * HID * 2);
    unsigned short* hc  = (unsigned short*)take((size_t)N_NODES * CLS * 2);

    const int NB_E = (N_EDGES + 255) / 256;
    const int NB_M64 = (N_NODES + 63) / 64;
    const int NB_WAVE = (N_NODES * 64 + 255) / 256;
    const int CVTN = IN_F * HID + HID * HID + HID * CLSP;

    hipMemsetAsync(zblk, 0, 3 * SZN, stream);

    k_deg<<<NB_E, 256, 0, stream>>>(src, dst, deg_out_i, deg_in_i);
    k_scan<<<1, 1024, 0, stream>>>(deg_in_i, deg_out_i, row_ptr, do_is, di_is);
    k_fill<<<NB_E, 256, 0, stream>>>(src, dst, row_ptr, cnt, col);

    k_lncvt<<<NB_WAVE, 256, 0, stream>>>(feat, g_in, b_in, Abf);
    k_cvtW_all<<<(CVTN + 255) / 256, 256, 0, stream>>>(W0, W1, W2, Wt0, Wt1, Wt2);

    // Layer 0
    k_gemm1_mfma<<<NB_M64, 256, 0, stream>>>(Abf, Wt0, do_is, h0);
    k_aggln<<<NB_WAVE, 256, 0, stream>>>(h0, row_ptr, col, di_is, do_is, g0, b0, (unsigned*)h1);

    // Layer 1
    k_agg128b<<<NB_WAVE, 256, 0, stream>>>(h1, row_ptr, col, (unsigned*)hb);
    k_gemm2ln<<<NB_M64, 256, 0, stream>>>(hb, Wt1, di_is, do_is, g1, b1, (unsigned*)h1);

    // Layer 2
    k_gemm3_mfma<<<NB_M64, 256, 0, stream>>>(h1, Wt2, hc);
    k_agg40b<<<NB_WAVE, 256, 0, stream>>>(hc, row_ptr, col, di_is, b2, out);
}

// Round 5
// 378.709 us; speedup vs baseline: 1.4553x; 1.4553x over previous
//
#include <hip/hip_runtime.h>
#include <math.h>

#define N_NODES 50000
#define N_EDGES 800000
#define IN_F 768
#define HID 128
#define CLS 40
#define CLSP 48
#define EPS 1e-5f
#define LNS 133  // padded LDS stride for gemm2ln tile

typedef __attribute__((ext_vector_type(8))) short short8;
typedef __attribute__((ext_vector_type(4))) float f32x4;

__device__ inline unsigned short f2bf(float f) {
    union { float f; unsigned u; } x;
    x.f = f;
    unsigned u = x.u;
    return (unsigned short)((u + 0x7FFF + ((u >> 16) & 1)) >> 16);
}

__device__ inline float bf2f(unsigned short u) {
    union { unsigned u; float f; } x;
    x.u = ((unsigned)u) << 16;
    return x.f;
}

__device__ inline unsigned pack2bf(float a, float b) {
    return (unsigned)f2bf(a) | ((unsigned)f2bf(b) << 16);
}

// ---------------- degree ----------------

__global__ void k_deg(const int* __restrict__ src, const int* __restrict__ dst,
                      int* __restrict__ deg_out, int* __restrict__ deg_in) {
    int e = blockIdx.x * 256 + threadIdx.x;
    if (e < N_EDGES) {
        atomicAdd(&deg_out[src[e]], 1);
        atomicAdd(&deg_in[dst[e]], 1);
    }
}

// ---------------- unordered segment offsets (no scan needed for CSR) ----------------
// Each wave: shfl_up prefix of degrees, one atomicAdd per wave for the base.
// start[i] = base + exclusive_prefix(i). Segment of node i = [start[i], start[i]+deg_in[i]).

__global__ void k_offsets(const int* __restrict__ deg_in, const int* __restrict__ deg_out,
                          int* __restrict__ start, float* __restrict__ do_is,
                          float* __restrict__ di_is, int* __restrict__ counter) {
    int i = blockIdx.x * 256 + threadIdx.x;
    int lane = threadIdx.x & 63;
    int d = (i < N_NODES) ? deg_in[i] : 0;
    int pre = d;
#pragma unroll
    for (int m = 1; m < 64; m <<= 1) {
        int v = __shfl_up(pre, m);
        if (lane >= m) pre += v;
    }
    int total = __shfl(pre, 63);
    int base = 0;
    if (lane == 63) base = atomicAdd(counter, total);
    base = __shfl(base, 63);
    if (i < N_NODES) {
        start[i] = base + pre - d;
        di_is[i] = rsqrtf((float)max(d, 1));
        do_is[i] = rsqrtf((float)max(deg_out[i], 1));
    }
}

__global__ void k_fill(const int* __restrict__ src, const int* __restrict__ dst,
                       const int* __restrict__ start, int* __restrict__ cnt,
                       int* __restrict__ col) {
    int e = blockIdx.x * 256 + threadIdx.x;
    if (e < N_EDGES) {
        int d = dst[e];
        int pos = start[d] + atomicAdd(&cnt[d], 1);
        col[pos] = src[e];
    }
}

// ---------------- fused LN(768) + bf16 convert (wave per row) ----------------

__global__ void k_lncvt(const float* __restrict__ feat, const float* __restrict__ g,
                        const float* __restrict__ b, unsigned short* __restrict__ Abf) {
    int wid = (blockIdx.x * 256 + threadIdx.x) >> 6;
    int lane = threadIdx.x & 63;
    if (wid >= N_NODES) return;
    const float4* x4 = (const float4*)(feat + (size_t)wid * IN_F);
    float4 v[3];
    float s = 0.f, q = 0.f;
#pragma unroll
    for (int i = 0; i < 3; i++) {
        float4 t = x4[lane + 64 * i];
        v[i] = t;
        s += t.x + t.y + t.z + t.w;
        q += t.x * t.x + t.y * t.y + t.z * t.z + t.w * t.w;
    }
#pragma unroll
    for (int m = 1; m < 64; m <<= 1) {
        s += __shfl_xor(s, m);
        q += __shfl_xor(q, m);
    }
    float mu = s * (1.f / (float)IN_F);
    float var = q * (1.f / (float)IN_F) - mu * mu;
    float rstd = rsqrtf(var + EPS);
    ushort4* orow = (ushort4*)(Abf + (size_t)wid * IN_F);
    const float4* g4 = (const float4*)g;
    const float4* b4 = (const float4*)b;
#pragma unroll
    for (int i = 0; i < 3; i++) {
        int f = lane + 64 * i;
        float4 gg = g4[f];
        float4 bb = b4[f];
        ushort4 o;
        o.x = f2bf((v[i].x - mu) * rstd * gg.x + bb.x);
        o.y = f2bf((v[i].y - mu) * rstd * gg.y + bb.y);
        o.z = f2bf((v[i].z - mu) * rstd * gg.z + bb.z);
        o.w = f2bf((v[i].w - mu) * rstd * gg.w + bb.w);
        orow[f] = o;
    }
}

// ---------------- all weight transposes+converts in one kernel ----------------

__global__ void k_cvtW_all(const float* __restrict__ W0, const float* __restrict__ W1,
                           const float* __restrict__ W2, unsigned short* __restrict__ Wt0,
                           unsigned short* __restrict__ Wt1, unsigned short* __restrict__ Wt2) {
    int idx = blockIdx.x * 256 + threadIdx.x;
    const int S0 = IN_F * HID;
    const int S1 = S0 + HID * HID;
    const int S2 = S1 + HID * CLSP;
    if (idx < S0) {
        int c = idx / IN_F, k = idx % IN_F;
        Wt0[idx] = f2bf(W0[(size_t)k * HID + c]);
    } else if (idx < S1) {
        int j = idx - S0;
        int c = j / HID, k = j % HID;
        Wt1[j] = f2bf(W1[(size_t)k * HID + c]);
    } else if (idx < S2) {
        int j = idx - S1;
        int c = j / HID, k = j % HID;
        Wt2[j] = (c < CLS) ? f2bf(W2[(size_t)k * CLS + c]) : (unsigned short)0;
    }
}

// ---------------- GEMM1 (MFMA): h0 = bf16( (Abf @ Wt0^T) * do_is[row] ) ----------------

__global__ void k_gemm1_mfma(const unsigned short* __restrict__ Abf,
                             const unsigned short* __restrict__ Wt,
                             const float* __restrict__ do_is,
                             unsigned short* __restrict__ out) {
    int t = threadIdx.x;
    int w = t >> 6, l = t & 63;
    int r0 = blockIdx.x * 64;
    int c0 = w * 32;
    int lrow = l & 15;
    int lk8 = (l >> 4);

    const short8* ap[4];
#pragma unroll
    for (int m = 0; m < 4; m++) {
        int row = r0 + m * 16 + lrow;
        if (row > N_NODES - 1) row = N_NODES - 1;
        ap[m] = (const short8*)(Abf + (size_t)row * IN_F) + lk8;
    }
    const short8* bp[2];
#pragma unroll
    for (int n = 0; n < 2; n++) {
        int colr = c0 + n * 16 + lrow;
        bp[n] = (const short8*)(Wt + (size_t)colr * IN_F) + lk8;
    }

    f32x4 acc[4][2] = {};
#pragma unroll
    for (int k0 = 0; k0 < IN_F / 8; k0 += 4) {
        short8 bv[2];
        bv[0] = bp[0][k0];
        bv[1] = bp[1][k0];
#pragma unroll
        for (int m = 0; m < 4; m++) {
            short8 av = ap[m][k0];
            acc[m][0] = __builtin_amdgcn_mfma_f32_16x16x32_bf16(av, bv[0], acc[m][0], 0, 0, 0);
            acc[m][1] = __builtin_amdgcn_mfma_f32_16x16x32_bf16(av, bv[1], acc[m][1], 0, 0, 0);
        }
    }

#pragma unroll
    for (int m = 0; m < 4; m++) {
#pragma unroll
        for (int j = 0; j < 4; j++) {
            int row = r0 + m * 16 + (l >> 4) * 4 + j;
            if (row < N_NODES) {
                float s = do_is[row];
                out[(size_t)row * HID + c0 + (l & 15)] = f2bf(acc[m][0][j] * s);
                out[(size_t)row * HID + c0 + 16 + (l & 15)] = f2bf(acc[m][1][j] * s);
            }
        }
    }
}

// ---------------- GEMM2 + LN + ReLU fused ----------------

__global__ void k_gemm2ln(const unsigned short* __restrict__ A,
                          const unsigned short* __restrict__ Wt,
                          const float* __restrict__ di_is, const float* __restrict__ do_is,
                          const float* __restrict__ g, const float* __restrict__ b,
                          unsigned* __restrict__ out) {
    __shared__ float tile[64 * LNS];
    int t = threadIdx.x;
    int w = t >> 6, l = t & 63;
    int r0 = blockIdx.x * 64;
    int c0 = w * 32;
    int lrow = l & 15;
    int lk8 = (l >> 4);

    const short8* ap[4];
#pragma unroll
    for (int m = 0; m < 4; m++) {
        int row = r0 + m * 16 + lrow;
        if (row > N_NODES - 1) row = N_NODES - 1;
        ap[m] = (const short8*)(A + (size_t)row * HID) + lk8;
    }
    const short8* bp[2];
#pragma unroll
    for (int n = 0; n < 2; n++) {
        int colr = c0 + n * 16 + lrow;
        bp[n] = (const short8*)(Wt + (size_t)colr * HID) + lk8;
    }

    f32x4 acc[4][2] = {};
#pragma unroll
    for (int k0 = 0; k0 < HID / 8; k0 += 4) {
        short8 bv[2];
        bv[0] = bp[0][k0];
        bv[1] = bp[1][k0];
#pragma unroll
        for (int m = 0; m < 4; m++) {
            short8 av = ap[m][k0];
            acc[m][0] = __builtin_amdgcn_mfma_f32_16x16x32_bf16(av, bv[0], acc[m][0], 0, 0, 0);
            acc[m][1] = __builtin_amdgcn_mfma_f32_16x16x32_bf16(av, bv[1], acc[m][1], 0, 0, 0);
        }
    }

#pragma unroll
    for (int m = 0; m < 4; m++) {
#pragma unroll
        for (int j = 0; j < 4; j++) {
            int rl = m * 16 + (l >> 4) * 4 + j;
            int grow = r0 + rl;
            float s = di_is[(grow < N_NODES) ? grow : (N_NODES - 1)];
            tile[rl * LNS + c0 + (l & 15)] = acc[m][0][j] * s;
            tile[rl * LNS + c0 + 16 + (l & 15)] = acc[m][1][j] * s;
        }
    }
    __syncthreads();

    int r = w * 16 + (l & 15);
    int q = l >> 4;
    float s1 = 0.f, s2 = 0.f;
#pragma unroll
    for (int c = 0; c < 32; c++) {
        float v = tile[r * LNS + q * 32 + c];
        s1 += v;
        s2 += v * v;
    }
    s1 += __shfl_xor(s1, 16); s2 += __shfl_xor(s2, 16);
    s1 += __shfl_xor(s1, 32); s2 += __shfl_xor(s2, 32);
    float mu = s1 * (1.f / 128.f);
    float var = s2 * (1.f / 128.f) - mu * mu;
    float rstd = rsqrtf(var + EPS);
    int grow = r0 + r;
    if (grow < N_NODES) {
        float sc = do_is[grow];
        unsigned* orow = out + (size_t)grow * 64 + q * 16;
        const float2* g2 = (const float2*)(g + q * 32);
        const float2* b2v = (const float2*)(b + q * 32);
#pragma unroll
        for (int cc = 0; cc < 16; cc++) {
            float v0 = tile[r * LNS + q * 32 + 2 * cc];
            float v1 = tile[r * LNS + q * 32 + 2 * cc + 1];
            float2 gg = g2[cc];
            float2 bb = b2v[cc];
            float y0 = fmaxf((v0 - mu) * rstd * gg.x + bb.x, 0.f) * sc;
            float y1 = fmaxf((v1 - mu) * rstd * gg.y + bb.y, 0.f) * sc;
            orow[cc] = pack2bf(y0, y1);
        }
    }
}

// ---------------- GEMM3 (MFMA): hc = bf16(h1 @ Wt2^T)  [M,128]x[128,40->48] ----------------

__global__ void k_gemm3_mfma(const unsigned short* __restrict__ A,
                             const unsigned short* __restrict__ Wt,
                             unsigned short* __restrict__ out) {
    int t = threadIdx.x;
    int w = t >> 6, l = t & 63;
    int r0 = blockIdx.x * 64 + w * 16;
    int lrow = l & 15;
    int lk8 = (l >> 4);

    int arow = r0 + lrow;
    if (arow > N_NODES - 1) arow = N_NODES - 1;
    const short8* ap = (const short8*)(A + (size_t)arow * HID) + lk8;
    const short8* bp[3];
#pragma unroll
    for (int n = 0; n < 3; n++) {
        int colr = n * 16 + lrow;
        bp[n] = (const short8*)(Wt + (size_t)colr * HID) + lk8;
    }

    f32x4 acc[3] = {};
#pragma unroll
    for (int k0 = 0; k0 < HID / 8; k0 += 4) {
        short8 av = ap[k0];
#pragma unroll
        for (int n = 0; n < 3; n++) {
            acc[n] = __builtin_amdgcn_mfma_f32_16x16x32_bf16(av, bp[n][k0], acc[n], 0, 0, 0);
        }
    }

#pragma unroll
    for (int n = 0; n < 3; n++) {
        int col = n * 16 + (l & 15);
        if (col < CLS) {
#pragma unroll
            for (int j = 0; j < 4; j++) {
                int row = r0 + (l >> 4) * 4 + j;
                if (row < N_NODES) out[(size_t)row * CLS + col] = f2bf(acc[n][j]);
            }
        }
    }
}

// ---------------- fused agg + LN + ReLU (layer 0), wave per node, 4x unrolled ----------------

__global__ void k_aggln(const unsigned short* __restrict__ h, const int* __restrict__ start,
                        const int* __restrict__ deg, const int* __restrict__ col,
                        const float* __restrict__ di_is, const float* __restrict__ do_is,
                        const float* __restrict__ g, const float* __restrict__ b,
                        unsigned* __restrict__ out) {
    int wid = (blockIdx.x * blockDim.x + threadIdx.x) >> 6;
    int lane = threadIdx.x & 63;
    if (wid >= N_NODES) return;
    int s0 = start[wid], e0 = s0 + deg[wid];
    const unsigned* h2 = (const unsigned*)h;
    float ax = 0.f, ay = 0.f;
    int i = s0;
    for (; i + 3 < e0; i += 4) {
        int c0_ = col[i], c1_ = col[i + 1], c2_ = col[i + 2], c3_ = col[i + 3];
        unsigned u0 = h2[(size_t)c0_ * 64 + lane];
        unsigned u1 = h2[(size_t)c1_ * 64 + lane];
        unsigned u2 = h2[(size_t)c2_ * 64 + lane];
        unsigned u3 = h2[(size_t)c3_ * 64 + lane];
        ax += bf2f((unsigned short)(u0 & 0xFFFF)) + bf2f((unsigned short)(u1 & 0xFFFF)) +
              bf2f((unsigned short)(u2 & 0xFFFF)) + bf2f((unsigned short)(u3 & 0xFFFF));
        ay += bf2f((unsigned short)(u0 >> 16)) + bf2f((unsigned short)(u1 >> 16)) +
              bf2f((unsigned short)(u2 >> 16)) + bf2f((unsigned short)(u3 >> 16));
    }
    for (; i < e0; i++) {
        unsigned u = h2[(size_t)col[i] * 64 + lane];
        ax += bf2f((unsigned short)(u & 0xFFFF));
        ay += bf2f((unsigned short)(u >> 16));
    }
    float di = di_is[wid];
    ax *= di; ay *= di;
    float s = ax + ay;
    float q = ax * ax + ay * ay;
#pragma unroll
    for (int m = 1; m < 64; m <<= 1) {
        s += __shfl_xor(s, m);
        q += __shfl_xor(q, m);
    }
    float mu = s * (1.f / 128.f);
    float var = q * (1.f / 128.f) - mu * mu;
    float rstd = rsqrtf(var + EPS);
    float2 gg = ((const float2*)g)[lane];
    float2 bb = ((const float2*)b)[lane];
    float sc = do_is[wid];
    float y0 = fmaxf((ax - mu) * rstd * gg.x + bb.x, 0.f) * sc;
    float y1 = fmaxf((ay - mu) * rstd * gg.y + bb.y, 0.f) * sc;
    out[(size_t)wid * 64 + lane] = pack2bf(y0, y1);
}

// ---------------- agg (layer 1), bf16 raw-sum out, wave per node, 4x unrolled ----------------

__global__ void k_agg128b(const unsigned short* __restrict__ h, const int* __restrict__ start,
                          const int* __restrict__ deg, const int* __restrict__ col,
                          unsigned* __restrict__ out) {
    int wid = (blockIdx.x * blockDim.x + threadIdx.x) >> 6;
    int lane = threadIdx.x & 63;
    if (wid >= N_NODES) return;
    int s0 = start[wid], e0 = s0 + deg[wid];
    const unsigned* h2 = (const unsigned*)h;
    float ax = 0.f, ay = 0.f;
    int i = s0;
    for (; i + 3 < e0; i += 4) {
        int c0_ = col[i], c1_ = col[i + 1], c2_ = col[i + 2], c3_ = col[i + 3];
        unsigned u0 = h2[(size_t)c0_ * 64 + lane];
        unsigned u1 = h2[(size_t)c1_ * 64 + lane];
        unsigned u2 = h2[(size_t)c2_ * 64 + lane];
        unsigned u3 = h2[(size_t)c3_ * 64 + lane];
        ax += bf2f((unsigned short)(u0 & 0xFFFF)) + bf2f((unsigned short)(u1 & 0xFFFF)) +
              bf2f((unsigned short)(u2 & 0xFFFF)) + bf2f((unsigned short)(u3 & 0xFFFF));
        ay += bf2f((unsigned short)(u0 >> 16)) + bf2f((unsigned short)(u1 >> 16)) +
              bf2f((unsigned short)(u2 >> 16)) + bf2f((unsigned short)(u3 >> 16));
    }
    for (; i < e0; i++) {
        unsigned u = h2[(size_t)col[i] * 64 + lane];
        ax += bf2f((unsigned short)(u & 0xFFFF));
        ay += bf2f((unsigned short)(u >> 16));
    }
    out[(size_t)wid * 64 + lane] = pack2bf(ax, ay);
}

// ---------------- agg (layer 2), 40 feats + bias, f32 out, wave per node, 4x unrolled ----------------

__global__ void k_agg40b(const unsigned short* __restrict__ h, const int* __restrict__ start,
                         const int* __restrict__ deg, const int* __restrict__ col,
                         const float* __restrict__ di_is, const float* __restrict__ b2,
                         float* __restrict__ out) {
    int wid = (blockIdx.x * blockDim.x + threadIdx.x) >> 6;
    int lane = threadIdx.x & 63;
    if (wid >= N_NODES) return;
    if (lane < CLS) {
        int s0 = start[wid], e0 = s0 + deg[wid];
        float acc = 0.f;
        int i = s0;
        for (; i + 3 < e0; i += 4) {
            int c0_ = col[i], c1_ = col[i + 1], c2_ = col[i + 2], c3_ = col[i + 3];
            float v0 = bf2f(h[(size_t)c0_ * CLS + lane]);
            float v1 = bf2f(h[(size_t)c1_ * CLS + lane]);
            float v2 = bf2f(h[(size_t)c2_ * CLS + lane]);
            float v3 = bf2f(h[(size_t)c3_ * CLS + lane]);
            acc += v0 + v1 + v2 + v3;
        }
        for (; i < e0; i++) acc += bf2f(h[(size_t)col[i] * CLS + lane]);
        out[(size_t)wid * CLS + lane] = acc * di_is[wid] + b2[lane];
    }
}

// ---------------- launch ----------------

extern "C" void kernel_launch(void* const* d_in, const int* in_sizes, int n_in,
                              void* d_out, int out_size, void* d_ws, size_t ws_size,
                              hipStream_t stream) {
    (void)in_sizes; (void)n_in; (void)out_size; (void)ws_size;
    const float* feat = (const float*)d_in[0];
    const int*   src  = (const int*)d_in[1];
    const int*   dst  = (const int*)d_in[2];
    const float* W0   = (const float*)d_in[3];
    const float* W1   = (const float*)d_in[4];
    const float* W2   = (const float*)d_in[5];
    const float* b2   = (const float*)d_in[6];
    const float* g_in = (const float*)d_in[7];
    const float* b_in = (const float*)d_in[8];
    const float* g0   = (const float*)d_in[9];
    const float* b0   = (const float*)d_in[10];
    const float* g1   = (const float*)d_in[11];
    const float* b1   = (const float*)d_in[12];
    float* out = (float*)d_out;

    char* w = (char*)d_ws;
    size_t off = 0;
    auto take = [&](size_t bytes) -> void* {
        void* p = w + off;
        off += (bytes + 255) & ~(size_t)255;
        return p;
    };
    // contiguous zeroed region: deg_out, deg_in, cnt, counter
    const size_t SZN = ((size_t)N_NODES * 4 + 255) & ~(size_t)255;
    char* zblk      = (char*)take(3 * SZN + 256);
    int*  deg_out_i = (int*)zblk;
    int*  deg_in_i  = (int*)(zblk + SZN);
    int*  cnt       = (int*)(zblk + 2 * SZN);
    int*  counter   = (int*)(zblk + 3 * SZN);

    float* do_is     = (float*)take((size_t)N_NODES * 4);
    float* di_is     = (float*)take((size_t)N_NODES * 4);
    int*   start     = (int*)take((size_t)N_NODES * 4);
    int*   col       = (int*)take((size_t)N_EDGES * 4);
    unsigned short* Abf = (unsigned short*)take((size_t)N_NODES * IN_F * 2);
    unsigned short* Wt0 = (unsigned short*)take((size_t)IN_F * HID * 2);
    unsigned short* Wt1 = (unsigned short*)take((size_t)HID * HID * 2);
    unsigned short* Wt2 = (unsigned short*)take((size_t)HID * CLSP * 2);
    unsigned short* h0  = (unsigned short*)take((size_t)N_NODES * HID * 2);
    unsigned short* h1  = (unsigned short*)take((size_t)N_NODES * HID * 2);
    unsigned short* hb  = (unsigned short*)take((size_t)N_NODES * HID * 2);
    unsigned short* hc  = (unsigned short*)take((size_t)N_NODES * CLS * 2);

    const int NB_E = (N_EDGES + 255) / 256;
    const int NB_N = (N_NODES + 255) / 256;
    const int NB_M64 = (N_NODES + 63) / 64;
    const int NB_WAVE = (N_NODES * 64 + 255) / 256;
    const int CVTN = IN_F * HID + HID * HID + HID * CLSP;

    hipMemsetAsync(zblk, 0, 3 * SZN + 256, stream);

    k_deg<<<NB_E, 256, 0, stream>>>(src, dst, deg_out_i, deg_in_i);
    k_offsets<<<NB_N, 256, 0, stream>>>(deg_in_i, deg_out_i, start, do_is, di_is, counter);
    k_fill<<<NB_E, 256, 0, stream>>>(src, dst, start, cnt, col);

    k_lncvt<<<NB_WAVE, 256, 0, stream>>>(feat, g_in, b_in, Abf);
    k_cvtW_all<<<(CVTN + 255) / 256, 256, 0, stream>>>(W0, W1, W2, Wt0, Wt1, Wt2);

    // Layer 0
    k_gemm1_mfma<<<NB_M64, 256, 0, stream>>>(Abf, Wt0, do_is, h0);
    k_aggln<<<NB_WAVE, 256, 0, stream>>>(h0, start, deg_in_i, col, di_is, do_is, g0, b0, (unsigned*)h1);

    // Layer 1
    k_agg128b<<<NB_WAVE, 256, 0, stream>>>(h1, start, deg_in_i, col, (unsigned*)hb);
    k_gemm2ln<<<NB_M64, 256, 0, stream>>>(hb, Wt1, di_is, do_is, g1, b1, (unsigned*)h1);

    // Layer 2
    k_gemm3_mfma<<<NB_M64, 256, 0, stream>>>(h1, Wt2, hc);
    k_agg40b<<<NB_WAVE, 256, 0, stream>>>(hc, start, deg_in_i, col, di_is, b2, out);
}

// Round 6
// 336.253 us; speedup vs baseline: 1.6390x; 1.1263x over previous
//
#include <hip/hip_runtime.h>
#include <math.h>

#define N_NODES 50000
#define N_EDGES 800000
#define IN_F 768
#define HID 128
#define CLS 40
#define CLSP 48
#define CSTRIDE 64   // padded row stride (shorts) for hc
#define EPS 1e-5f
#define LNS 133      // padded f32 LDS stride for gemm2ln tile
#define AS_STR 776   // padded bf16 LDS stride (shorts) for lngemm1 A tile

typedef __attribute__((ext_vector_type(8))) short short8;
typedef __attribute__((ext_vector_type(4))) float f32x4;

__device__ inline unsigned short f2bf(float f) {
    union { float f; unsigned u; } x;
    x.f = f;
    unsigned u = x.u;
    return (unsigned short)((u + 0x7FFF + ((u >> 16) & 1)) >> 16);
}

__device__ inline float bf2f(unsigned short u) {
    union { unsigned u; float f; } x;
    x.u = ((unsigned)u) << 16;
    return x.f;
}

__device__ inline unsigned pack2bf(float a, float b) {
    return (unsigned)f2bf(a) | ((unsigned)f2bf(b) << 16);
}

// ---------------- degree ----------------

__global__ void k_deg(const int* __restrict__ src, const int* __restrict__ dst,
                      int* __restrict__ deg_out, int* __restrict__ deg_in) {
    int e = blockIdx.x * 256 + threadIdx.x;
    if (e < N_EDGES) {
        atomicAdd(&deg_out[src[e]], 1);
        atomicAdd(&deg_in[dst[e]], 1);
    }
}

// ---------------- unordered segment offsets (wave prefix + one atomic per wave) ----------------

__global__ void k_offsets(const int* __restrict__ deg_in, const int* __restrict__ deg_out,
                          int* __restrict__ start, float* __restrict__ do_is,
                          float* __restrict__ di_is, int* __restrict__ counter) {
    int i = blockIdx.x * 256 + threadIdx.x;
    int lane = threadIdx.x & 63;
    int d = (i < N_NODES) ? deg_in[i] : 0;
    int pre = d;
#pragma unroll
    for (int m = 1; m < 64; m <<= 1) {
        int v = __shfl_up(pre, m);
        if (lane >= m) pre += v;
    }
    int total = __shfl(pre, 63);
    int base = 0;
    if (lane == 63) base = atomicAdd(counter, total);
    base = __shfl(base, 63);
    if (i < N_NODES) {
        start[i] = base + pre - d;
        di_is[i] = rsqrtf((float)max(d, 1));
        do_is[i] = rsqrtf((float)max(deg_out[i], 1));
    }
}

__global__ void k_fill(const int* __restrict__ src, const int* __restrict__ dst,
                       const int* __restrict__ start, int* __restrict__ cnt,
                       int* __restrict__ col) {
    int e = blockIdx.x * 256 + threadIdx.x;
    if (e < N_EDGES) {
        int d = dst[e];
        int pos = start[d] + atomicAdd(&cnt[d], 1);
        col[pos] = src[e];
    }
}

// ---------------- all weight transposes+converts in one kernel ----------------

__global__ void k_cvtW_all(const float* __restrict__ W0, const float* __restrict__ W1,
                           const float* __restrict__ W2, unsigned short* __restrict__ Wt0,
                           unsigned short* __restrict__ Wt1, unsigned short* __restrict__ Wt2) {
    int idx = blockIdx.x * 256 + threadIdx.x;
    const int S0 = IN_F * HID;
    const int S1 = S0 + HID * HID;
    const int S2 = S1 + HID * CLSP;
    if (idx < S0) {
        int c = idx / IN_F, k = idx % IN_F;
        Wt0[idx] = f2bf(W0[(size_t)k * HID + c]);
    } else if (idx < S1) {
        int j = idx - S0;
        int c = j / HID, k = j % HID;
        Wt1[j] = f2bf(W1[(size_t)k * HID + c]);
    } else if (idx < S2) {
        int j = idx - S1;
        int c = j / HID, k = j % HID;
        Wt2[j] = (c < CLS) ? f2bf(W2[(size_t)k * CLS + c]) : (unsigned short)0;
    }
}

// ---------------- fused LN(768) + GEMM1 (MFMA) ----------------
// h0 = bf16( (LN(feat)@W0) * do_is[row] ),  [M,768]x[768,128]
// Block: 256 thr (4 waves), 32 rows. Phase 1: wave-per-row LN -> LDS bf16 tile.
// Phase 2: wave w computes 32 rows x 32 cols (m-frags 2, n-frags 2), A from LDS, B from L2.

__global__ void k_lngemm1(const float* __restrict__ feat, const float* __restrict__ g,
                          const float* __restrict__ b, const unsigned short* __restrict__ Wt,
                          const float* __restrict__ do_is, unsigned short* __restrict__ out) {
    __shared__ unsigned short As[32 * AS_STR];  // 48.5 KB
    int t = threadIdx.x;
    int w = t >> 6, l = t & 63;
    int r0 = blockIdx.x * 32;

    // ---- phase 1: LN rows w*8 .. w*8+7 ----
    const float4* g4 = (const float4*)g;
    const float4* b4 = (const float4*)b;
    for (int rr = 0; rr < 8; rr++) {
        int lr = w * 8 + rr;
        int grow = r0 + lr;
        if (grow > N_NODES - 1) grow = N_NODES - 1;
        const float4* x4 = (const float4*)(feat + (size_t)grow * IN_F);
        float4 v[3];
        float s = 0.f, q = 0.f;
#pragma unroll
        for (int i = 0; i < 3; i++) {
            float4 tv = x4[l + 64 * i];
            v[i] = tv;
            s += tv.x + tv.y + tv.z + tv.w;
            q += tv.x * tv.x + tv.y * tv.y + tv.z * tv.z + tv.w * tv.w;
        }
#pragma unroll
        for (int m = 1; m < 64; m <<= 1) {
            s += __shfl_xor(s, m);
            q += __shfl_xor(q, m);
        }
        float mu = s * (1.f / (float)IN_F);
        float var = q * (1.f / (float)IN_F) - mu * mu;
        float rstd = rsqrtf(var + EPS);
        ushort4* arow = (ushort4*)(&As[lr * AS_STR]);
#pragma unroll
        for (int i = 0; i < 3; i++) {
            int f = l + 64 * i;
            float4 gg = g4[f];
            float4 bb = b4[f];
            ushort4 o;
            o.x = f2bf((v[i].x - mu) * rstd * gg.x + bb.x);
            o.y = f2bf((v[i].y - mu) * rstd * gg.y + bb.y);
            o.z = f2bf((v[i].z - mu) * rstd * gg.z + bb.z);
            o.w = f2bf((v[i].w - mu) * rstd * gg.w + bb.w);
            arow[f] = o;
        }
    }
    __syncthreads();

    // ---- phase 2: MFMA ----
    int c0 = w * 32;
    int lrow = l & 15;
    int lk8 = l >> 4;

    const short8* bp[2];
#pragma unroll
    for (int n = 0; n < 2; n++) {
        int colr = c0 + n * 16 + lrow;
        bp[n] = (const short8*)(Wt + (size_t)colr * IN_F) + lk8;
    }
    int rowm[2] = {lrow, 16 + lrow};

    f32x4 acc[2][2] = {};
#pragma unroll
    for (int k0 = 0; k0 < IN_F / 8; k0 += 4) {
        short8 bv0 = bp[0][k0];
        short8 bv1 = bp[1][k0];
#pragma unroll
        for (int m = 0; m < 2; m++) {
            short8 av = *(const short8*)(&As[rowm[m] * AS_STR + (lk8 + k0) * 8]);
            acc[m][0] = __builtin_amdgcn_mfma_f32_16x16x32_bf16(av, bv0, acc[m][0], 0, 0, 0);
            acc[m][1] = __builtin_amdgcn_mfma_f32_16x16x32_bf16(av, bv1, acc[m][1], 0, 0, 0);
        }
    }

#pragma unroll
    for (int m = 0; m < 2; m++) {
#pragma unroll
        for (int j = 0; j < 4; j++) {
            int row = r0 + m * 16 + (l >> 4) * 4 + j;
            if (row < N_NODES) {
                float s = do_is[row];
                out[(size_t)row * HID + c0 + (l & 15)] = f2bf(acc[m][0][j] * s);
                out[(size_t)row * HID + c0 + 16 + (l & 15)] = f2bf(acc[m][1][j] * s);
            }
        }
    }
}

// ---------------- GEMM2 + LN + ReLU fused ----------------

__global__ void k_gemm2ln(const unsigned short* __restrict__ A,
                          const unsigned short* __restrict__ Wt,
                          const float* __restrict__ di_is, const float* __restrict__ do_is,
                          const float* __restrict__ g, const float* __restrict__ b,
                          unsigned* __restrict__ out) {
    __shared__ float tile[64 * LNS];
    int t = threadIdx.x;
    int w = t >> 6, l = t & 63;
    int r0 = blockIdx.x * 64;
    int c0 = w * 32;
    int lrow = l & 15;
    int lk8 = (l >> 4);

    const short8* ap[4];
#pragma unroll
    for (int m = 0; m < 4; m++) {
        int row = r0 + m * 16 + lrow;
        if (row > N_NODES - 1) row = N_NODES - 1;
        ap[m] = (const short8*)(A + (size_t)row * HID) + lk8;
    }
    const short8* bp[2];
#pragma unroll
    for (int n = 0; n < 2; n++) {
        int colr = c0 + n * 16 + lrow;
        bp[n] = (const short8*)(Wt + (size_t)colr * HID) + lk8;
    }

    f32x4 acc[4][2] = {};
#pragma unroll
    for (int k0 = 0; k0 < HID / 8; k0 += 4) {
        short8 bv[2];
        bv[0] = bp[0][k0];
        bv[1] = bp[1][k0];
#pragma unroll
        for (int m = 0; m < 4; m++) {
            short8 av = ap[m][k0];
            acc[m][0] = __builtin_amdgcn_mfma_f32_16x16x32_bf16(av, bv[0], acc[m][0], 0, 0, 0);
            acc[m][1] = __builtin_amdgcn_mfma_f32_16x16x32_bf16(av, bv[1], acc[m][1], 0, 0, 0);
        }
    }

#pragma unroll
    for (int m = 0; m < 4; m++) {
#pragma unroll
        for (int j = 0; j < 4; j++) {
            int rl = m * 16 + (l >> 4) * 4 + j;
            int grow = r0 + rl;
            float s = di_is[(grow < N_NODES) ? grow : (N_NODES - 1)];
            tile[rl * LNS + c0 + (l & 15)] = acc[m][0][j] * s;
            tile[rl * LNS + c0 + 16 + (l & 15)] = acc[m][1][j] * s;
        }
    }
    __syncthreads();

    int r = w * 16 + (l & 15);
    int q = l >> 4;
    float s1 = 0.f, s2 = 0.f;
#pragma unroll
    for (int c = 0; c < 32; c++) {
        float v = tile[r * LNS + q * 32 + c];
        s1 += v;
        s2 += v * v;
    }
    s1 += __shfl_xor(s1, 16); s2 += __shfl_xor(s2, 16);
    s1 += __shfl_xor(s1, 32); s2 += __shfl_xor(s2, 32);
    float mu = s1 * (1.f / 128.f);
    float var = s2 * (1.f / 128.f) - mu * mu;
    float rstd = rsqrtf(var + EPS);
    int grow = r0 + r;
    if (grow < N_NODES) {
        float sc = do_is[grow];
        unsigned* orow = out + (size_t)grow * 64 + q * 16;
        const float2* g2 = (const float2*)(g + q * 32);
        const float2* b2v = (const float2*)(b + q * 32);
#pragma unroll
        for (int cc = 0; cc < 16; cc++) {
            float v0 = tile[r * LNS + q * 32 + 2 * cc];
            float v1 = tile[r * LNS + q * 32 + 2 * cc + 1];
            float2 gg = g2[cc];
            float2 bb = b2v[cc];
            float y0 = fmaxf((v0 - mu) * rstd * gg.x + bb.x, 0.f) * sc;
            float y1 = fmaxf((v1 - mu) * rstd * gg.y + bb.y, 0.f) * sc;
            orow[cc] = pack2bf(y0, y1);
        }
    }
}

// ---------------- GEMM3 (MFMA): hc = bf16(h1 @ Wt2^T), row stride 64 ----------------

__global__ void k_gemm3_mfma(const unsigned short* __restrict__ A,
                             const unsigned short* __restrict__ Wt,
                             unsigned short* __restrict__ out) {
    int t = threadIdx.x;
    int w = t >> 6, l = t & 63;
    int r0 = blockIdx.x * 64 + w * 16;
    int lrow = l & 15;
    int lk8 = (l >> 4);

    int arow = r0 + lrow;
    if (arow > N_NODES - 1) arow = N_NODES - 1;
    const short8* ap = (const short8*)(A + (size_t)arow * HID) + lk8;
    const short8* bp[3];
#pragma unroll
    for (int n = 0; n < 3; n++) {
        int colr = n * 16 + lrow;
        bp[n] = (const short8*)(Wt + (size_t)colr * HID) + lk8;
    }

    f32x4 acc[3] = {};
#pragma unroll
    for (int k0 = 0; k0 < HID / 8; k0 += 4) {
        short8 av = ap[k0];
#pragma unroll
        for (int n = 0; n < 3; n++) {
            acc[n] = __builtin_amdgcn_mfma_f32_16x16x32_bf16(av, bp[n][k0], acc[n], 0, 0, 0);
        }
    }

#pragma unroll
    for (int n = 0; n < 3; n++) {
        int col = n * 16 + (l & 15);
#pragma unroll
        for (int j = 0; j < 4; j++) {
            int row = r0 + (l >> 4) * 4 + j;
            if (row < N_NODES) out[(size_t)row * CSTRIDE + col] = f2bf(acc[n][j]);
        }
    }
}

// ---------------- fused agg + LN + ReLU (layer 0), wave per node, 4x unrolled ----------------

__global__ void k_aggln(const unsigned short* __restrict__ h, const int* __restrict__ start,
                        const int* __restrict__ deg, const int* __restrict__ col,
                        const float* __restrict__ di_is, const float* __restrict__ do_is,
                        const float* __restrict__ g, const float* __restrict__ b,
                        unsigned* __restrict__ out) {
    int wid = (blockIdx.x * blockDim.x + threadIdx.x) >> 6;
    int lane = threadIdx.x & 63;
    if (wid >= N_NODES) return;
    int s0 = start[wid], e0 = s0 + deg[wid];
    const unsigned* h2 = (const unsigned*)h;
    float ax = 0.f, ay = 0.f;
    int i = s0;
    for (; i + 3 < e0; i += 4) {
        int c0_ = col[i], c1_ = col[i + 1], c2_ = col[i + 2], c3_ = col[i + 3];
        unsigned u0 = h2[(size_t)c0_ * 64 + lane];
        unsigned u1 = h2[(size_t)c1_ * 64 + lane];
        unsigned u2 = h2[(size_t)c2_ * 64 + lane];
        unsigned u3 = h2[(size_t)c3_ * 64 + lane];
        ax += bf2f((unsigned short)(u0 & 0xFFFF)) + bf2f((unsigned short)(u1 & 0xFFFF)) +
              bf2f((unsigned short)(u2 & 0xFFFF)) + bf2f((unsigned short)(u3 & 0xFFFF));
        ay += bf2f((unsigned short)(u0 >> 16)) + bf2f((unsigned short)(u1 >> 16)) +
              bf2f((unsigned short)(u2 >> 16)) + bf2f((unsigned short)(u3 >> 16));
    }
    for (; i < e0; i++) {
        unsigned u = h2[(size_t)col[i] * 64 + lane];
        ax += bf2f((unsigned short)(u & 0xFFFF));
        ay += bf2f((unsigned short)(u >> 16));
    }
    float di = di_is[wid];
    ax *= di; ay *= di;
    float s = ax + ay;
    float q = ax * ax + ay * ay;
#pragma unroll
    for (int m = 1; m < 64; m <<= 1) {
        s += __shfl_xor(s, m);
        q += __shfl_xor(q, m);
    }
    float mu = s * (1.f / 128.f);
    float var = q * (1.f / 128.f) - mu * mu;
    float rstd = rsqrtf(var + EPS);
    float2 gg = ((const float2*)g)[lane];
    float2 bb = ((const float2*)b)[lane];
    float sc = do_is[wid];
    float y0 = fmaxf((ax - mu) * rstd * gg.x + bb.x, 0.f) * sc;
    float y1 = fmaxf((ay - mu) * rstd * gg.y + bb.y, 0.f) * sc;
    out[(size_t)wid * 64 + lane] = pack2bf(y0, y1);
}

// ---------------- agg (layer 1), bf16 raw-sum out, wave per node, 4x unrolled ----------------

__global__ void k_agg128b(const unsigned short* __restrict__ h, const int* __restrict__ start,
                          const int* __restrict__ deg, const int* __restrict__ col,
                          unsigned* __restrict__ out) {
    int wid = (blockIdx.x * blockDim.x + threadIdx.x) >> 6;
    int lane = threadIdx.x & 63;
    if (wid >= N_NODES) return;
    int s0 = start[wid], e0 = s0 + deg[wid];
    const unsigned* h2 = (const unsigned*)h;
    float ax = 0.f, ay = 0.f;
    int i = s0;
    for (; i + 3 < e0; i += 4) {
        int c0_ = col[i], c1_ = col[i + 1], c2_ = col[i + 2], c3_ = col[i + 3];
        unsigned u0 = h2[(size_t)c0_ * 64 + lane];
        unsigned u1 = h2[(size_t)c1_ * 64 + lane];
        unsigned u2 = h2[(size_t)c2_ * 64 + lane];
        unsigned u3 = h2[(size_t)c3_ * 64 + lane];
        ax += bf2f((unsigned short)(u0 & 0xFFFF)) + bf2f((unsigned short)(u1 & 0xFFFF)) +
              bf2f((unsigned short)(u2 & 0xFFFF)) + bf2f((unsigned short)(u3 & 0xFFFF));
        ay += bf2f((unsigned short)(u0 >> 16)) + bf2f((unsigned short)(u1 >> 16)) +
              bf2f((unsigned short)(u2 >> 16)) + bf2f((unsigned short)(u3 >> 16));
    }
    for (; i < e0; i++) {
        unsigned u = h2[(size_t)col[i] * 64 + lane];
        ax += bf2f((unsigned short)(u & 0xFFFF));
        ay += bf2f((unsigned short)(u >> 16));
    }
    out[(size_t)wid * 64 + lane] = pack2bf(ax, ay);
}

// ---------------- agg (layer 2), padded 64-stride rows, wave per node ----------------

__global__ void k_agg40b(const unsigned short* __restrict__ h, const int* __restrict__ start,
                         const int* __restrict__ deg, const int* __restrict__ col,
                         const float* __restrict__ di_is, const float* __restrict__ b2,
                         float* __restrict__ out) {
    int wid = (blockIdx.x * blockDim.x + threadIdx.x) >> 6;
    int lane = threadIdx.x & 63;
    if (wid >= N_NODES) return;
    int s0 = start[wid], e0 = s0 + deg[wid];
    float acc = 0.f;
    int i = s0;
    for (; i + 3 < e0; i += 4) {
        int c0_ = col[i], c1_ = col[i + 1], c2_ = col[i + 2], c3_ = col[i + 3];
        float v0 = bf2f(h[(size_t)c0_ * CSTRIDE + lane]);
        float v1 = bf2f(h[(size_t)c1_ * CSTRIDE + lane]);
        float v2 = bf2f(h[(size_t)c2_ * CSTRIDE + lane]);
        float v3 = bf2f(h[(size_t)c3_ * CSTRIDE + lane]);
        acc += v0 + v1 + v2 + v3;
    }
    for (; i < e0; i++) acc += bf2f(h[(size_t)col[i] * CSTRIDE + lane]);
    if (lane < CLS) out[(size_t)wid * CLS + lane] = acc * di_is[wid] + b2[lane];
}

// ---------------- launch ----------------

extern "C" void kernel_launch(void* const* d_in, const int* in_sizes, int n_in,
                              void* d_out, int out_size, void* d_ws, size_t ws_size,
                              hipStream_t stream) {
    (void)in_sizes; (void)n_in; (void)out_size; (void)ws_size;
    const float* feat = (const float*)d_in[0];
    const int*   src  = (const int*)d_in[1];
    const int*   dst  = (const int*)d_in[2];
    const float* W0   = (const float*)d_in[3];
    const float* W1   = (const float*)d_in[4];
    const float* W2   = (const float*)d_in[5];
    const float* b2   = (const float*)d_in[6];
    const float* g_in = (const float*)d_in[7];
    const float* b_in = (const float*)d_in[8];
    const float* g0   = (const float*)d_in[9];
    const float* b0   = (const float*)d_in[10];
    const float* g1   = (const float*)d_in[11];
    const float* b1   = (const float*)d_in[12];
    float* out = (float*)d_out;

    char* w = (char*)d_ws;
    size_t off = 0;
    auto take = [&](size_t bytes) -> void* {
        void* p = w + off;
        off += (bytes + 255) & ~(size_t)255;
        return p;
    };
    const size_t SZN = ((size_t)N_NODES * 4 + 255) & ~(size_t)255;
    char* zblk      = (char*)take(3 * SZN + 256);
    int*  deg_out_i = (int*)zblk;
    int*  deg_in_i  = (int*)(zblk + SZN);
    int*  cnt       = (int*)(zblk + 2 * SZN);
    int*  counter   = (int*)(zblk + 3 * SZN);

    float* do_is     = (float*)take((size_t)N_NODES * 4);
    float* di_is     = (float*)take((size_t)N_NODES * 4);
    int*   start     = (int*)take((size_t)N_NODES * 4);
    int*   col       = (int*)take((size_t)N_EDGES * 4);
    unsigned short* Wt0 = (unsigned short*)take((size_t)IN_F * HID * 2);
    unsigned short* Wt1 = (unsigned short*)take((size_t)HID * HID * 2);
    unsigned short* Wt2 = (unsigned short*)take((size_t)HID * CLSP * 2);
    unsigned short* h0  = (unsigned short*)take((size_t)N_NODES * HID * 2);
    unsigned short* h1  = (unsigned short*)take((size_t)N_NODES * HID * 2);
    unsigned short* hb  = (unsigned short*)take((size_t)N_NODES * HID * 2);
    unsigned short* hc  = (unsigned short*)take((size_t)N_NODES * CSTRIDE * 2);

    const int NB_E = (N_EDGES + 255) / 256;
    const int NB_N = (N_NODES + 255) / 256;
    const int NB_M32 = (N_NODES + 31) / 32;
    const int NB_M64 = (N_NODES + 63) / 64;
    const int NB_WAVE = (N_NODES * 64 + 255) / 256;
    const int CVTN = IN_F * HID + HID * HID + HID * CLSP;

    hipMemsetAsync(zblk, 0, 3 * SZN + 256, stream);

    k_deg<<<NB_E, 256, 0, stream>>>(src, dst, deg_out_i, deg_in_i);
    k_offsets<<<NB_N, 256, 0, stream>>>(deg_in_i, deg_out_i, start, do_is, di_is, counter);
    k_fill<<<NB_E, 256, 0, stream>>>(src, dst, start, cnt, col);

    k_cvtW_all<<<(CVTN + 255) / 256, 256, 0, stream>>>(W0, W1, W2, Wt0, Wt1, Wt2);

    // Layer 0: h0 = (LN(feat)@W0)*do_is ; h1 = relu(LN(agg(h0)*di_is))*do_is
    k_lngemm1<<<NB_M32, 256, 0, stream>>>(feat, g_in, b_in, Wt0, do_is, h0);
    k_aggln<<<NB_WAVE, 256, 0, stream>>>(h0, start, deg_in_i, col, di_is, do_is, g0, b0, (unsigned*)h1);

    // Layer 1: hb = agg(h1) ; h1 = relu(LN((hb@W1)*di_is))*do_is
    k_agg128b<<<NB_WAVE, 256, 0, stream>>>(h1, start, deg_in_i, col, (unsigned*)hb);
    k_gemm2ln<<<NB_M64, 256, 0, stream>>>(hb, Wt1, di_is, do_is, g1, b1, (unsigned*)h1);

    // Layer 2: hc = h1@W2 (padded stride) ; out = agg(hc)*di_is + b2
    k_gemm3_mfma<<<NB_M64, 256, 0, stream>>>(h1, Wt2, hc);
    k_agg40b<<<NB_WAVE, 256, 0, stream>>>(hc, start, deg_in_i, col, di_is, b2, out);
}